// Round 10
// baseline (264.139 us; speedup 1.0000x reference)
//
#include <hip/hip_runtime.h>
#include <math.h>

#define BN_SCALE_F 0.99999500003749969f

// x: [N=64][T=300][C=64][V=25] fp32
// pooled: [N*C=4096][T=300]
// kern:   [4096][3]
// la:     [4096][300]
// W1P:    [75][600][4]  (W1P[k4][j][kk] = g_w1[j][k4*4+kk])
// lw1r:   [64][48]      (lw1r[c][o*3+k] = l_w1[o][c][k])

// ---------------- Kernel 1: mean over V (blocks 0..4799) + weight repack (4800..4850) ----------------
__global__ __launch_bounds__(256) void pool_prep_kernel(const float* __restrict__ x,
                                                        const float* __restrict__ g_w1,
                                                        const float* __restrict__ l_w1,
                                                        float* __restrict__ pooled,
                                                        float* __restrict__ w1p,
                                                        float* __restrict__ lw1r) {
  __shared__ float buf[6400];
  int bid = blockIdx.x;
  if (bid < 4800) {
    const float4* src = (const float4*)(x + (size_t)bid * 6400);
    float4* b4 = (float4*)buf;
    for (int i = threadIdx.x; i < 1600; i += 256) b4[i] = src[i];
    __syncthreads();
    int wave = threadIdx.x >> 6;
    int c = threadIdx.x & 63;
    int nt = bid * 4 + wave;
    int n = nt / 300, t = nt - n * 300;
    const float* p = buf + wave * 1600 + c * 25;
    float s = 0.f;
#pragma unroll
    for (int v = 0; v < 25; ++v) s += p[v];
    pooled[((size_t)(n * 64 + c)) * 300 + t] = s * 0.04f;
  } else if (bid < 4850) {
    int b = bid - 4800;  // 0..49: transpose g_w1 tile 64x64
    float* tile = buf;   // [64][65]
    int tj = b % 10, tk = b / 10;
    int j0 = tj * 64, k0 = tk * 64;
    for (int it = 0; it < 16; ++it) {
      int i = threadIdx.x + it * 256;
      int jj = i >> 6, kk = i & 63;
      int j = j0 + jj, k = k0 + kk;
      tile[jj * 65 + kk] = (j < 600 && k < 300) ? g_w1[(size_t)j * 300 + k] : 0.f;
    }
    __syncthreads();
    for (int it = 0; it < 16; ++it) {
      int jloc = threadIdx.x >> 2;
      int kkm = threadIdx.x & 3;
      int kloc = it * 4 + kkm;
      int j = j0 + jloc, k = k0 + kloc;
      if (j < 600 && k < 300) {
        w1p[(size_t)(k >> 2) * 2400 + (size_t)j * 4 + (k & 3)] = tile[jloc * 65 + kloc];
      }
    }
  } else {
    // repack l_w1 [16][64][3] -> [64][48]
    for (int i = threadIdx.x; i < 3072; i += 256) {
      int o = i / 192;
      int rem = i - o * 192;
      int c = rem / 3;
      int k = rem - c * 3;
      lw1r[c * 48 + o * 3 + k] = l_w1[i];
    }
  }
}

// ---------------- Kernel 2: G branch — 2x8 register tile per thread ----------------
// 16 rows/block, 256 blocks, 640 threads (10 waves). Thread (rt,jt): rows 2rt..2rt+1,
// cols jt*8..jt*8+7. Per k4: 2 broadcast ds_read_b128 + 8 coalesced-line weight b128
// feed 64 FMA -> LDS-pipe demand cut 16x vs 1-col/thread; VALU-bound.
__global__ __launch_bounds__(640) void g_kernel(const float* __restrict__ pooled,
                                                const float* __restrict__ w1p,   // [75][600][4]
                                                const float* __restrict__ g_w2,  // [3][600]
                                                float* __restrict__ kern) {      // [4096][3]
  __shared__ float rows[16][300];  // 19.2 KB
  __shared__ float hbuf[16][640];  // 40.96 KB (cols >=600 zeroed)
  __shared__ float logits[48];
  int r0 = blockIdx.x * 16;
  int tid = threadIdx.x;
  {
    const float4* src = (const float4*)(pooled + (size_t)r0 * 300);
    float4* dst = (float4*)&rows[0][0];
    for (int i = tid; i < 1200; i += 640) dst[i] = src[i];
  }
  __syncthreads();

  int rt = tid / 80;        // 0..7 -> rows 2rt, 2rt+1
  int jt = tid - rt * 80;   // 0..79 -> cols jt*8..jt*8+7
  int j0 = jt * 8;
  bool act = (j0 < 600);
  int j0c = act ? j0 : 0;
  const float4* wp = (const float4*)w1p;  // [75][600]

  float acc[2][8];
#pragma unroll
  for (int i = 0; i < 2; ++i)
#pragma unroll
    for (int q = 0; q < 8; ++q) acc[i][q] = 0.f;

  float4 wv[8], wn[8];
#pragma unroll
  for (int q = 0; q < 8; ++q) wv[q] = wp[j0c + q];

  for (int k4 = 0; k4 < 75; ++k4) {
    int nk = (k4 < 74) ? k4 + 1 : 74;
#pragma unroll
    for (int q = 0; q < 8; ++q) wn[q] = wp[(size_t)nk * 600 + j0c + q];
    float4 rv0 = *(const float4*)(&rows[rt * 2 + 0][k4 * 4]);  // broadcast
    float4 rv1 = *(const float4*)(&rows[rt * 2 + 1][k4 * 4]);
#pragma unroll
    for (int q = 0; q < 8; ++q) {
      acc[0][q] = fmaf(rv0.x, wv[q].x, acc[0][q]);
      acc[0][q] = fmaf(rv0.y, wv[q].y, acc[0][q]);
      acc[0][q] = fmaf(rv0.z, wv[q].z, acc[0][q]);
      acc[0][q] = fmaf(rv0.w, wv[q].w, acc[0][q]);
      acc[1][q] = fmaf(rv1.x, wv[q].x, acc[1][q]);
      acc[1][q] = fmaf(rv1.y, wv[q].y, acc[1][q]);
      acc[1][q] = fmaf(rv1.z, wv[q].z, acc[1][q]);
      acc[1][q] = fmaf(rv1.w, wv[q].w, acc[1][q]);
    }
#pragma unroll
    for (int q = 0; q < 8; ++q) wv[q] = wn[q];
  }

#pragma unroll
  for (int i = 0; i < 2; ++i)
#pragma unroll
    for (int q = 0; q < 8; ++q) {
      float h = fmaxf(acc[i][q] * BN_SCALE_F, 0.f);
      hbuf[rt * 2 + i][j0 + q] = act ? h : 0.f;  // inactive threads zero cols 600..639
    }
  __syncthreads();

  int wave = tid >> 6, lane = tid & 63;
  for (int o = wave; o < 48; o += 10) {
    int r = o / 3, k = o - r * 3;
    float s = 0.f;
#pragma unroll
    for (int q = 0; q < 10; ++q) {
      int jj = lane + q * 64;
      float wz = (jj < 600) ? g_w2[k * 600 + jj] : 0.f;
      s = fmaf(hbuf[r][jj], wz, s);
    }
#pragma unroll
    for (int off = 1; off < 64; off <<= 1) s += __shfl_xor(s, off, 64);
    if (lane == 0) logits[o] = s;
  }
  __syncthreads();
  if (tid < 16) {
    float a = logits[tid * 3 + 0], b = logits[tid * 3 + 1], c = logits[tid * 3 + 2];
    float m = fmaxf(a, fmaxf(b, c));
    float ea = expf(a - m), eb = expf(b - m), ec = expf(c - m);
    float inv = 1.f / (ea + eb + ec);
    size_t oo = (size_t)(r0 + tid) * 3;
    kern[oo] = ea * inv;
    kern[oo + 1] = eb * inv;
    kern[oo + 2] = ec * inv;
  }
}

// ---------------- Kernel 3: L branch — split into 4 t-chunks (grid 256) ----------------
__global__ __launch_bounds__(320) void l_kernel(const float* __restrict__ pooled,
                                                const float* __restrict__ lw1r,  // [64][48]
                                                const float* __restrict__ l_w2,  // [64][16]
                                                float* __restrict__ la) {        // [4096][300]
  __shared__ float p[64][80];  // tt 0..76 = global t0-1 .. t0+75 (zeros outside)
  __shared__ float z[75][20];  // z[tl][o], 16 used, pad 20 (float4-aligned rows)
  int bid = blockIdx.x;
  int n = bid >> 2;
  int tc = bid & 3;
  int t0 = tc * 75;
  for (int i = threadIdx.x; i < 64 * 77; i += 320) {
    int c = i / 77, tt = i - c * 77;
    int gt = t0 - 1 + tt;
    p[c][tt] = (gt >= 0 && gt < 300) ? pooled[(size_t)(n * 64 + c) * 300 + gt] : 0.f;
  }
  __syncthreads();
  {
    int og = threadIdx.x / 80;        // 0..3 -> outs og*4..og*4+3
    int tl = threadIdx.x - og * 80;   // 0..79; active < 75
    if (tl < 75) {
      float acc[4] = {0.f, 0.f, 0.f, 0.f};
      for (int c = 0; c < 64; ++c) {
        const float* wr = lw1r + c * 48 + og * 12;  // uniform -> s_load
        float pk0 = p[c][tl];
        float pk1 = p[c][tl + 1];
        float pk2 = p[c][tl + 2];
#pragma unroll
        for (int oi = 0; oi < 4; ++oi) {
          acc[oi] = fmaf(wr[oi * 3 + 0], pk0, acc[oi]);
          acc[oi] = fmaf(wr[oi * 3 + 1], pk1, acc[oi]);
          acc[oi] = fmaf(wr[oi * 3 + 2], pk2, acc[oi]);
        }
      }
      float4 zv;
      zv.x = fmaxf(acc[0] * BN_SCALE_F, 0.f);
      zv.y = fmaxf(acc[1] * BN_SCALE_F, 0.f);
      zv.z = fmaxf(acc[2] * BN_SCALE_F, 0.f);
      zv.w = fmaxf(acc[3] * BN_SCALE_F, 0.f);
      *(float4*)(&z[tl][og * 4]) = zv;
    }
  }
  __syncthreads();
  {
    int c = threadIdx.x / 5;
    int ts = threadIdx.x - c * 5;
    const float4* w2v = (const float4*)(l_w2 + c * 16);
    float4 wA = w2v[0], wB = w2v[1], wC = w2v[2], wD = w2v[3];
    float* outp = la + (size_t)(n * 64 + c) * 300 + t0;
    for (int it = 0; it < 15; ++it) {
      int tl = ts + it * 5;  // 0..74
      const float4* zv = (const float4*)(&z[tl][0]);
      float4 zA = zv[0], zB = zv[1], zC = zv[2], zD = zv[3];
      float s = zA.x * wA.x + zA.y * wA.y + zA.z * wA.z + zA.w * wA.w;
      s += zB.x * wB.x + zB.y * wB.y + zB.z * wB.z + zB.w * wB.w;
      s += zC.x * wC.x + zC.y * wC.y + zC.z * wC.z + zC.w * wC.w;
      s += zD.x * wD.x + zD.y * wD.y + zD.z * wD.z + zD.w * wD.w;
      outp[tl] = 1.f / (1.f + expf(-s));
    }
  }
}

// ---------------- Kernel 4: final conv — LDS la + depth-2 x prefetch ----------------
__global__ __launch_bounds__(256) void tam_final_kernel(const float* __restrict__ x,
                                                        const float* __restrict__ la,
                                                        const float* __restrict__ kern,
                                                        float* __restrict__ out) {
  __shared__ float la_s[64][40];  // t0-1 .. t0+38
  int bid = blockIdx.x;  // 64 n * 8 tchunk * 2 half
  int n = bid >> 4;
  int rem = bid & 15;
  int tch = rem >> 1;
  int half = rem & 1;
  int t0 = tch * 38;
  for (int i = threadIdx.x; i < 2560; i += 256) {
    int c = i / 40, tt = i - c * 40;
    int gt = t0 - 1 + tt;
    la_s[c][tt] = (gt >= 0 && gt < 300) ? la[(size_t)(n * 64 + c) * 300 + gt] : 0.f;
  }
  __syncthreads();

  int cv4 = half * 256 + threadIdx.x;
  if (cv4 >= 400) return;
  int e0 = cv4 * 4;
  int c0 = e0 / 25;
  int c3 = (e0 + 3) / 25;
  bool s1 = ((e0 + 1) / 25) != c0;
  bool s2 = ((e0 + 2) / 25) != c0;
  bool s3 = (c3 != c0);
  const float* kp0 = kern + (size_t)(n * 64 + c0) * 3;
  const float* kp1 = kern + (size_t)(n * 64 + c3) * 3;
  float k00 = kp0[0], k01 = kp0[1], k02 = kp0[2];
  float k10 = kp1[0], k11 = kp1[1], k12 = kp1[2];
  float4 K0 = {k00, s1 ? k10 : k00, s2 ? k10 : k00, s3 ? k10 : k00};
  float4 K1 = {k01, s1 ? k11 : k01, s2 ? k11 : k01, s3 ? k11 : k01};
  float4 K2 = {k02, s1 ? k12 : k02, s2 ? k12 : k02, s3 ? k12 : k02};

  const float4* xp = (const float4*)(x + (size_t)n * 480000) + cv4;  // +t*400
  float4* op = (float4*)(out + (size_t)n * 480000) + cv4;

  int tend = t0 + 38;
  if (tend > 300) tend = 300;

#define YMAKE(dst, XV, IDX)                  \
  {                                          \
    float l0 = la_s[c0][(IDX)];              \
    float l1 = la_s[c3][(IDX)];              \
    dst.x = XV.x * l0;                       \
    dst.y = XV.y * (s1 ? l1 : l0);           \
    dst.z = XV.z * (s2 ? l1 : l0);           \
    dst.w = XV.w * (s3 ? l1 : l0);           \
  }

  float4 am, ac;
  if (t0 > 0) {
    float4 xv = xp[(size_t)(t0 - 1) * 400];
    YMAKE(am, xv, 0);
  } else {
    am = {0.f, 0.f, 0.f, 0.f};
  }
  {
    float4 xv = xp[(size_t)t0 * 400];
    YMAKE(ac, xv, 1);
  }
  float4 xn1 = xp[(size_t)(t0 + 1) * 400];
  float4 xn2 = xp[(size_t)(t0 + 2 < 300 ? t0 + 2 : 299) * 400];

  for (int t = t0; t < tend; ++t) {
    int t3 = t + 3;
    if (t3 > 299) t3 = 299;
    float4 xn3 = xp[(size_t)t3 * 400];
    float4 an;
    if (t + 1 < 300) {
      YMAKE(an, xn1, t - t0 + 2);
    } else {
      an = {0.f, 0.f, 0.f, 0.f};
    }
    float4 o;
    o.x = fmaf(am.x, K0.x, fmaf(ac.x, K1.x, an.x * K2.x));
    o.y = fmaf(am.y, K0.y, fmaf(ac.y, K1.y, an.y * K2.y));
    o.z = fmaf(am.z, K0.z, fmaf(ac.z, K1.z, an.z * K2.z));
    o.w = fmaf(am.w, K0.w, fmaf(ac.w, K1.w, an.w * K2.w));
    op[(size_t)t * 400] = o;
    am = ac;
    ac = an;
    xn1 = xn2;
    xn2 = xn3;
  }
#undef YMAKE
}

extern "C" void kernel_launch(void* const* d_in, const int* in_sizes, int n_in,
                              void* d_out, int out_size, void* d_ws, size_t ws_size,
                              hipStream_t stream) {
  const float* x = (const float*)d_in[0];
  const float* g_w1 = (const float*)d_in[1];
  const float* g_w2 = (const float*)d_in[2];
  const float* l_w1 = (const float*)d_in[3];
  const float* l_w2 = (const float*)d_in[4];
  float* out = (float*)d_out;
  float* ws = (float*)d_ws;
  float* pooled = ws;                           // 1,228,800 floats
  float* kern = ws + 1228800;                   // 12,288
  float* lact = ws + 1228800 + 12288;           // 1,228,800
  float* w1p = ws + 1228800 + 12288 + 1228800;  // 180,000
  float* lw1r = w1p + 180000;                   // 3,072

  hipLaunchKernelGGL(pool_prep_kernel, dim3(4851), dim3(256), 0, stream, x, g_w1, l_w1,
                     pooled, w1p, lw1r);
  hipLaunchKernelGGL(g_kernel, dim3(256), dim3(640), 0, stream, pooled, w1p, g_w2, kern);
  hipLaunchKernelGGL(l_kernel, dim3(256), dim3(320), 0, stream, pooled, lw1r, l_w2, lact);
  hipLaunchKernelGGL(tam_final_kernel, dim3(1024), dim3(256), 0, stream, x, lact, kern, out);
}

// Round 11
// 122.159 us; speedup vs baseline: 2.1623x; 2.1623x over previous
//
#include <hip/hip_runtime.h>
#include <math.h>

#define BN_SCALE_F 0.99999500003749969f

// x: [N=64][T=300][C=64][V=25] fp32
// pooled: [N*C=4096][T=300]
// kern:   [4096][3]
// la:     [4096][300]
// W1P:    [75][600][4]  (W1P[k4][j][kk] = g_w1[j][k4*4+kk])
// lw1r:   [64][48]      (lw1r[c][o*3+k] = l_w1[o][c][k])

// ---------------- Kernel 1: mean over V (blocks 0..4799) + weight repack (4800..4850) ----------------
__global__ __launch_bounds__(256) void pool_prep_kernel(const float* __restrict__ x,
                                                        const float* __restrict__ g_w1,
                                                        const float* __restrict__ l_w1,
                                                        float* __restrict__ pooled,
                                                        float* __restrict__ w1p,
                                                        float* __restrict__ lw1r) {
  __shared__ float buf[6400];
  int bid = blockIdx.x;
  if (bid < 4800) {
    const float4* src = (const float4*)(x + (size_t)bid * 6400);
    float4* b4 = (float4*)buf;
    for (int i = threadIdx.x; i < 1600; i += 256) b4[i] = src[i];
    __syncthreads();
    int wave = threadIdx.x >> 6;
    int c = threadIdx.x & 63;
    int nt = bid * 4 + wave;
    int n = nt / 300, t = nt - n * 300;
    const float* p = buf + wave * 1600 + c * 25;
    float s = 0.f;
#pragma unroll
    for (int v = 0; v < 25; ++v) s += p[v];
    pooled[((size_t)(n * 64 + c)) * 300 + t] = s * 0.04f;
  } else if (bid < 4850) {
    int b = bid - 4800;  // 0..49: transpose g_w1 tile 64x64
    float* tile = buf;   // [64][65]
    int tj = b % 10, tk = b / 10;
    int j0 = tj * 64, k0 = tk * 64;
    for (int it = 0; it < 16; ++it) {
      int i = threadIdx.x + it * 256;
      int jj = i >> 6, kk = i & 63;
      int j = j0 + jj, k = k0 + kk;
      tile[jj * 65 + kk] = (j < 600 && k < 300) ? g_w1[(size_t)j * 300 + k] : 0.f;
    }
    __syncthreads();
    for (int it = 0; it < 16; ++it) {
      int jloc = threadIdx.x >> 2;
      int kkm = threadIdx.x & 3;
      int kloc = it * 4 + kkm;
      int j = j0 + jloc, k = k0 + kloc;
      if (j < 600 && k < 300) {
        w1p[(size_t)(k >> 2) * 2400 + (size_t)j * 4 + (k & 3)] = tile[jloc * 65 + kloc];
      }
    }
  } else {
    // repack l_w1 [16][64][3] -> [64][48]
    for (int i = threadIdx.x; i < 3072; i += 256) {
      int o = i / 192;
      int rem = i - o * 192;
      int c = rem / 3;
      int k = rem - c * 3;
      lw1r[c * 48 + o * 3 + k] = l_w1[i];
    }
  }
}

// ---------------- Kernel 2: merged G + L branch ----------------
// Blocks 0..511: G (round-4 structure: 8 rows, 320 thr, 2 cols/thread).
// Blocks 512..767: L (round-10 structure: n x t-chunk, 320 thr).
// G is LDS-pipe-bound, L is VALU-bound -> co-resident blocks overlap pipes.
union GLSmem {
  struct {
    float rows[8][300];
    float wsum[5][24];
  } g;
  struct {
    float p[64][80];   // tt 0..76 = t0-1 .. t0+75
    float z[75][20];   // [tl][o] padded
  } l;
};

__global__ __launch_bounds__(320) void gl_kernel(const float* __restrict__ pooled,
                                                 const float* __restrict__ w1p,   // [75][600][4]
                                                 const float* __restrict__ g_w2,  // [3][600]
                                                 const float* __restrict__ lw1r,  // [64][48]
                                                 const float* __restrict__ l_w2,  // [64][16]
                                                 float* __restrict__ kern,        // [4096][3]
                                                 float* __restrict__ la) {        // [4096][300]
  __shared__ GLSmem sm;
  int bid = blockIdx.x;
  int tid = threadIdx.x;
  if (bid < 512) {
    // ---- G branch ----
    int r0 = bid * 8;
    {
      const float4* src = (const float4*)(pooled + (size_t)r0 * 300);
      float4* dst = (float4*)&sm.g.rows[0][0];
      for (int i = tid; i < 600; i += 320) dst[i] = src[i];
    }
    __syncthreads();

    int j1 = tid;
    int j2 = tid + 320;
    bool has2 = (j2 < 600);
    int j2c = has2 ? j2 : j1;
    const float4* wp = (const float4*)w1p;  // [75][600]

    float acc1[8], acc2[8];
#pragma unroll
    for (int r = 0; r < 8; ++r) { acc1[r] = 0.f; acc2[r] = 0.f; }

    float4 wa = wp[j1];
    float4 wb = wp[j2c];
    for (int k4 = 0; k4 < 75; ++k4) {
      float4 wan, wbn;
      if (k4 < 74) {
        wan = wp[(size_t)(k4 + 1) * 600 + j1];
        wbn = wp[(size_t)(k4 + 1) * 600 + j2c];
      } else {
        wan = wa;
        wbn = wb;
      }
#pragma unroll
      for (int r = 0; r < 8; ++r) {
        float4 rv = *(const float4*)(&sm.g.rows[r][k4 * 4]);  // broadcast
        acc1[r] = fmaf(rv.x, wa.x, acc1[r]);
        acc1[r] = fmaf(rv.y, wa.y, acc1[r]);
        acc1[r] = fmaf(rv.z, wa.z, acc1[r]);
        acc1[r] = fmaf(rv.w, wa.w, acc1[r]);
        acc2[r] = fmaf(rv.x, wb.x, acc2[r]);
        acc2[r] = fmaf(rv.y, wb.y, acc2[r]);
        acc2[r] = fmaf(rv.z, wb.z, acc2[r]);
        acc2[r] = fmaf(rv.w, wb.w, acc2[r]);
      }
      wa = wan;
      wb = wbn;
    }

    float w2a0 = g_w2[j1], w2a1 = g_w2[600 + j1], w2a2 = g_w2[1200 + j1];
    float w2b0 = g_w2[j2c], w2b1 = g_w2[600 + j2c], w2b2 = g_w2[1200 + j2c];

    float lacc[24];
#pragma unroll
    for (int r = 0; r < 8; ++r) {
      float h1 = fmaxf(acc1[r] * BN_SCALE_F, 0.f);
      float h2 = has2 ? fmaxf(acc2[r] * BN_SCALE_F, 0.f) : 0.f;
      lacc[r * 3 + 0] = fmaf(h1, w2a0, h2 * w2b0);
      lacc[r * 3 + 1] = fmaf(h1, w2a1, h2 * w2b1);
      lacc[r * 3 + 2] = fmaf(h1, w2a2, h2 * w2b2);
    }

#pragma unroll
    for (int off = 1; off < 64; off <<= 1) {
#pragma unroll
      for (int i = 0; i < 24; ++i) lacc[i] += __shfl_xor(lacc[i], off, 64);
    }
    int wave = tid >> 6;
    int lane = tid & 63;
    if (lane == 0) {
#pragma unroll
      for (int i = 0; i < 24; ++i) sm.g.wsum[wave][i] = lacc[i];
    }
    __syncthreads();
    if (wave == 0) {
      float s = 0.f;
      if (lane < 24) {
#pragma unroll
        for (int w = 0; w < 5; ++w) s += sm.g.wsum[w][lane];
      }
      float a = __shfl(s, lane * 3 + 0, 64);
      float b = __shfl(s, lane * 3 + 1, 64);
      float c = __shfl(s, lane * 3 + 2, 64);
      if (lane < 8) {
        float m = fmaxf(a, fmaxf(b, c));
        float ea = expf(a - m), eb = expf(b - m), ec = expf(c - m);
        float inv = 1.f / (ea + eb + ec);
        size_t o = (size_t)(r0 + lane) * 3;
        kern[o] = ea * inv;
        kern[o + 1] = eb * inv;
        kern[o + 2] = ec * inv;
      }
    }
  } else {
    // ---- L branch ----
    int bid2 = bid - 512;
    int n = bid2 >> 2;
    int tc = bid2 & 3;
    int t0 = tc * 75;
    for (int i = tid; i < 64 * 77; i += 320) {
      int c = i / 77, tt = i - c * 77;
      int gt = t0 - 1 + tt;
      sm.l.p[c][tt] = (gt >= 0 && gt < 300) ? pooled[(size_t)(n * 64 + c) * 300 + gt] : 0.f;
    }
    __syncthreads();
    {
      int og = tid / 80;       // 0..3 -> outs og*4..og*4+3
      int tl = tid - og * 80;  // 0..79; active < 75
      if (tl < 75) {
        float acc[4] = {0.f, 0.f, 0.f, 0.f};
        for (int c = 0; c < 64; ++c) {
          const float* wr = lw1r + c * 48 + og * 12;  // uniform -> s_load
          float pk0 = sm.l.p[c][tl];
          float pk1 = sm.l.p[c][tl + 1];
          float pk2 = sm.l.p[c][tl + 2];
#pragma unroll
          for (int oi = 0; oi < 4; ++oi) {
            acc[oi] = fmaf(wr[oi * 3 + 0], pk0, acc[oi]);
            acc[oi] = fmaf(wr[oi * 3 + 1], pk1, acc[oi]);
            acc[oi] = fmaf(wr[oi * 3 + 2], pk2, acc[oi]);
          }
        }
        float4 zv;
        zv.x = fmaxf(acc[0] * BN_SCALE_F, 0.f);
        zv.y = fmaxf(acc[1] * BN_SCALE_F, 0.f);
        zv.z = fmaxf(acc[2] * BN_SCALE_F, 0.f);
        zv.w = fmaxf(acc[3] * BN_SCALE_F, 0.f);
        *(float4*)(&sm.l.z[tl][og * 4]) = zv;
      }
    }
    __syncthreads();
    {
      int c = tid / 5;
      int ts = tid - c * 5;
      const float4* w2v = (const float4*)(l_w2 + c * 16);
      float4 wA = w2v[0], wB = w2v[1], wC = w2v[2], wD = w2v[3];
      float* outp = la + (size_t)(n * 64 + c) * 300 + t0;
      for (int it = 0; it < 15; ++it) {
        int tl = ts + it * 5;  // 0..74
        const float4* zv = (const float4*)(&sm.l.z[tl][0]);
        float4 zA = zv[0], zB = zv[1], zC = zv[2], zD = zv[3];
        float s = zA.x * wA.x + zA.y * wA.y + zA.z * wA.z + zA.w * wA.w;
        s += zB.x * wB.x + zB.y * wB.y + zB.z * wB.z + zB.w * wB.w;
        s += zC.x * wC.x + zC.y * wC.y + zC.z * wC.z + zC.w * wC.w;
        s += zD.x * wD.x + zD.y * wD.y + zD.z * wD.z + zD.w * wD.w;
        outp[tl] = 1.f / (1.f + expf(-s));
      }
    }
  }
}

// ---------------- Kernel 4: final depthwise temporal conv (round-4 float4 form) ----------------
__global__ __launch_bounds__(256) void tam_final_kernel(const float* __restrict__ x,
                                                        const float* __restrict__ la,
                                                        const float* __restrict__ kern,
                                                        float* __restrict__ out) {
  int bid = blockIdx.x;  // 64 n * 8 tchunk * 2 half
  int n = bid >> 4;
  int rem = bid & 15;
  int tch = rem >> 1;
  int half = rem & 1;
  int cv4 = half * 256 + threadIdx.x;
  if (cv4 >= 400) return;
  int e0 = cv4 * 4;
  int c0 = e0 / 25;
  int c3 = (e0 + 3) / 25;
  bool s1 = ((e0 + 1) / 25) != c0;
  bool s2 = ((e0 + 2) / 25) != c0;
  bool s3 = (c3 != c0);
  const float* lap0 = la + (size_t)(n * 64 + c0) * 300;
  const float* lap1 = la + (size_t)(n * 64 + c3) * 300;
  const float* kp0 = kern + (size_t)(n * 64 + c0) * 3;
  const float* kp1 = kern + (size_t)(n * 64 + c3) * 3;
  float k00 = kp0[0], k01 = kp0[1], k02 = kp0[2];
  float k10 = kp1[0], k11 = kp1[1], k12 = kp1[2];
  float4 K0 = {k00, s1 ? k10 : k00, s2 ? k10 : k00, s3 ? k10 : k00};
  float4 K1 = {k01, s1 ? k11 : k01, s2 ? k11 : k01, s3 ? k11 : k01};
  float4 K2 = {k02, s1 ? k12 : k02, s2 ? k12 : k02, s3 ? k12 : k02};

  const float4* xp = (const float4*)(x + (size_t)n * 480000) + cv4;  // +t*400
  float4* op = (float4*)(out + (size_t)n * 480000) + cv4;

  int t0 = tch * 38;
  int tend = t0 + 38;
  if (tend > 300) tend = 300;

#define LAMUL(dst, t)                                        \
  {                                                          \
    float l0 = lap0[(t)];                                    \
    float l1 = lap1[(t)];                                    \
    float4 xv = xp[(size_t)(t) * 400];                       \
    dst.x = xv.x * l0;                                       \
    dst.y = xv.y * (s1 ? l1 : l0);                           \
    dst.z = xv.z * (s2 ? l1 : l0);                           \
    dst.w = xv.w * (s3 ? l1 : l0);                           \
  }

  float4 am, ac, an;
  if (t0 > 0) {
    LAMUL(am, t0 - 1);
  } else {
    am = {0.f, 0.f, 0.f, 0.f};
  }
  LAMUL(ac, t0);
  for (int t = t0; t < tend; ++t) {
    if (t + 1 < 300) {
      LAMUL(an, t + 1);
    } else {
      an = {0.f, 0.f, 0.f, 0.f};
    }
    float4 o;
    o.x = fmaf(am.x, K0.x, fmaf(ac.x, K1.x, an.x * K2.x));
    o.y = fmaf(am.y, K0.y, fmaf(ac.y, K1.y, an.y * K2.y));
    o.z = fmaf(am.z, K0.z, fmaf(ac.z, K1.z, an.z * K2.z));
    o.w = fmaf(am.w, K0.w, fmaf(ac.w, K1.w, an.w * K2.w));
    op[(size_t)t * 400] = o;
    am = ac;
    ac = an;
  }
#undef LAMUL
}

extern "C" void kernel_launch(void* const* d_in, const int* in_sizes, int n_in,
                              void* d_out, int out_size, void* d_ws, size_t ws_size,
                              hipStream_t stream) {
  const float* x = (const float*)d_in[0];
  const float* g_w1 = (const float*)d_in[1];
  const float* g_w2 = (const float*)d_in[2];
  const float* l_w1 = (const float*)d_in[3];
  const float* l_w2 = (const float*)d_in[4];
  float* out = (float*)d_out;
  float* ws = (float*)d_ws;
  float* pooled = ws;                           // 1,228,800 floats
  float* kern = ws + 1228800;                   // 12,288
  float* lact = ws + 1228800 + 12288;           // 1,228,800
  float* w1p = ws + 1228800 + 12288 + 1228800;  // 180,000
  float* lw1r = w1p + 180000;                   // 3,072

  hipLaunchKernelGGL(pool_prep_kernel, dim3(4851), dim3(256), 0, stream, x, g_w1, l_w1,
                     pooled, w1p, lw1r);
  hipLaunchKernelGGL(gl_kernel, dim3(768), dim3(320), 0, stream, pooled, w1p, g_w2,
                     lw1r, l_w2, kern, lact);
  hipLaunchKernelGGL(tam_final_kernel, dim3(1024), dim3(256), 0, stream, x, lact, kern, out);
}